// Round 11
// baseline (140.251 us; speedup 1.0000x reference)
//
#include <hip/hip_runtime.h>

// TsSub: out[b, p, t] = x[b, I[p], t*10] - x[b, J[p], t*10]
// x: (256, 64, 2000) f32, out: (256, 2016, 200) f32, (I,J)=triu_indices(64,k=1)
//
// R11 = R8 (fused combo-split, G=16, XCD swizzle) with ONE change:
// plain cached stores instead of nontemporal stores (A/B the nt write path).

#define NF      64
#define T_OUT   200
#define NPAIR   2016
#define NB      256
#define RF4     500             // vec4 per x row
#define TV4     50              // vec4 per out row
#define SPADF   208             // floats per LDS row (52 vec4)
#define NCOMBO  10
#define NWG     (NB * NCOMBO)   // 2560

typedef float fx4 __attribute__((ext_vector_type(4)));

__constant__ unsigned char kGi[NCOMBO] = {0,1,2,3, 0,0,0,1,1,2};
__constant__ unsigned char kGj[NCOMBO] = {0,1,2,3, 1,2,3,2,3,3};

__global__ __launch_bounds__(256)
void ts_sub_combo(const fx4* __restrict__ xv, fx4* __restrict__ out) {
    __shared__ __attribute__((aligned(16))) float sf[32 * SPADF];  // 26 KB
    __shared__ int obase[256];
    __shared__ unsigned char ir[256];
    __shared__ unsigned char jr[256];

    const int tid = threadIdx.x;
    // bijective XCD-chunk swizzle (2560 % 8 == 0): same-b combos contiguous
    const int n   = blockIdx.x;
    const int blk = (n & 7) * (NWG / 8) + (n >> 3);
    const int b     = blk / NCOMBO;
    const int combo = blk - b * NCOMBO;
    const int gi    = kGi[combo];
    const int gj    = kGj[combo];
    const bool diag = combo < 4;
    const int nrows  = diag ? 16 : 32;
    const int npairs = diag ? 120 : 256;

    // --- pair tables ---
    if (tid < npairs) {
        int il, jl;
        if (diag) {
            il = 0;                                   // base16(i) = i*(31-i)/2
            while ((il + 1) * (30 - il) / 2 <= tid) ++il;
            jl = tid - il * (31 - il) / 2 + il + 1;
            ir[tid] = (unsigned char)il;
            jr[tid] = (unsigned char)jl;
        } else {
            il = tid >> 4; jl = tid & 15;
            ir[tid] = (unsigned char)il;
            jr[tid] = (unsigned char)(16 + jl);
        }
        int i = gi * 16 + il;
        int j = (diag ? gi : gj) * 16 + jl;
        obase[tid] = i * (127 - i) / 2 + (j - i - 1);
    }

    // --- stage sampled rows directly from x ---
    // k in [0,200): u=k>>1, par=k&1, m=5u+2par, sample = par ? .z : .x
    {
        const fx4* __restrict__ xb = xv + (size_t)b * (NF * RF4);
        int idx = tid;                    // [0, nrows*200)
        int slot = 0;
        int k = tid;
        if (k >= T_OUT) { slot = 1; k -= T_OUT; }     // tid < 256 < 400
        const int total = nrows * T_OUT;
        while (idx < total) {
            int f = (slot < 16) ? (gi * 16 + slot) : (gj * 16 + slot - 16);
            int u = k >> 1, par = k & 1;
            fx4 v = xb[f * RF4 + 5 * u + 2 * par];
            sf[slot * SPADF + k] = par ? v.z : v.x;
            idx += 256;                   // 256 = 1*200 + 56
            slot += 1;
            k += 56;
            if (k >= T_OUT) { k -= T_OUT; ++slot; }
        }
    }
    __syncthreads();

    // --- emit pair rows: incremental (slot,t4), step 256 = 5*50 + 6 ---
    const fx4* __restrict__ s4 = reinterpret_cast<const fx4*>(sf); // row stride 52
    fx4* __restrict__ ob = out + (size_t)b * (NPAIR * TV4);
    const int total = npairs * TV4;          // 12800 or 6000
    int v    = tid;
    int slot = v / TV4;
    int t4   = v - slot * TV4;
    while (v < total) {
        fx4 a = s4[ir[slot] * 52 + t4];
        fx4 c = s4[jr[slot] * 52 + t4];
        fx4 r = a - c;
        ob[(size_t)obase[slot] * TV4 + t4] = r;   // plain cached store (was nt)
        v += 256;
        slot += 5;
        t4 += 6;
        if (t4 >= TV4) { t4 -= TV4; ++slot; }
    }
}

extern "C" void kernel_launch(void* const* d_in, const int* in_sizes, int n_in,
                              void* d_out, int out_size, void* d_ws, size_t ws_size,
                              hipStream_t stream) {
    const float* x = (const float*)d_in[0];
    float* out = (float*)d_out;
    ts_sub_combo<<<dim3(NWG), dim3(256), 0, stream>>>(
        (const fx4*)x, (fx4*)out);
}

// Round 12
// 106.789 us; speedup vs baseline: 1.3133x; 1.3133x over previous
//
#include <hip/hip_runtime.h>

// TsSub: out[b, p, t] = x[b, I[p], t*10] - x[b, J[p], t*10]
// x: (256, 64, 2000) f32, out: (256, 2016, 200) f32, (I,J)=triu_indices(64,k=1)
//
// R12 = R8 (fused combo-split, G=16, XCD swizzle, nt stores) with 512
// threads/block and unpadded LDS: 4 blocks/CU x 8 waves = 32 waves/CU (100%
// occupancy, vs 20). nt stores kept (R11 A/B: plain stores +30us regression).

#define NF      64
#define T_OUT   200
#define NPAIR   2016
#define NB      256
#define RF4     500             // vec4 per x row
#define TV4     50              // vec4 per out row
#define SROW    200             // floats per LDS row (unpadded)
#define NCOMBO  10
#define NWG     (NB * NCOMBO)   // 2560
#define NT      512

typedef float fx4 __attribute__((ext_vector_type(4)));

__constant__ unsigned char kGi[NCOMBO] = {0,1,2,3, 0,0,0,1,1,2};
__constant__ unsigned char kGj[NCOMBO] = {0,1,2,3, 1,2,3,2,3,3};

__global__ __launch_bounds__(NT)
void ts_sub_combo(const fx4* __restrict__ xv, fx4* __restrict__ out) {
    __shared__ __attribute__((aligned(16))) float sf[32 * SROW];  // 25.6 KB
    __shared__ int obase[256];
    __shared__ unsigned char ir[256];
    __shared__ unsigned char jr[256];

    const int tid = threadIdx.x;
    // bijective XCD-chunk swizzle (2560 % 8 == 0): same-b combos contiguous
    const int n   = blockIdx.x;
    const int blk = (n & 7) * (NWG / 8) + (n >> 3);
    const int b     = blk / NCOMBO;
    const int combo = blk - b * NCOMBO;
    const int gi    = kGi[combo];
    const int gj    = kGj[combo];
    const bool diag = combo < 4;
    const int nrows  = diag ? 16 : 32;
    const int npairs = diag ? 120 : 256;

    // --- pair tables (single pass, tid < 256 does the work) ---
    if (tid < npairs) {
        int il, jl;
        if (diag) {
            il = 0;                                   // base16(i) = i*(31-i)/2
            while ((il + 1) * (30 - il) / 2 <= tid) ++il;
            jl = tid - il * (31 - il) / 2 + il + 1;
            ir[tid] = (unsigned char)il;
            jr[tid] = (unsigned char)jl;
        } else {
            il = tid >> 4; jl = tid & 15;
            ir[tid] = (unsigned char)il;
            jr[tid] = (unsigned char)(16 + jl);
        }
        int i = gi * 16 + il;
        int j = (diag ? gi : gj) * 16 + jl;
        obase[tid] = i * (127 - i) / 2 + (j - i - 1);
    }

    // --- stage sampled rows directly from x ---
    // k in [0,200): u=k>>1, par=k&1, m=5u+2par, sample = par ? .z : .x
    {
        const fx4* __restrict__ xb = xv + (size_t)b * (NF * RF4);
        int slot = 0;
        int k = tid;
        if (k >= T_OUT) { slot = 1; k -= T_OUT; }
        if (k >= T_OUT) { slot = 2; k -= T_OUT; }     // tid < 512 < 600
        const int total = nrows * T_OUT;              // 3200 or 6400
        for (int idx = tid; idx < total; idx += NT) {
            int f = (slot < 16) ? (gi * 16 + slot) : (gj * 16 + slot - 16);
            int u = k >> 1, par = k & 1;
            fx4 v = xb[f * RF4 + 5 * u + 2 * par];
            sf[slot * SROW + k] = par ? v.z : v.x;
            slot += 2;                                // 512 = 2*200 + 112
            k += 112;
            if (k >= T_OUT) { k -= T_OUT; ++slot; }
        }
    }
    __syncthreads();

    // --- emit pair rows: incremental (slot,t4), step 512 = 10*50 + 12 ---
    const fx4* __restrict__ s4 = reinterpret_cast<const fx4*>(sf); // row stride 50
    fx4* __restrict__ ob = out + (size_t)b * (NPAIR * TV4);
    const int total = npairs * TV4;          // 12800 or 6000
    int v    = tid;
    int slot = v / TV4;
    int t4   = v - slot * TV4;
    while (v < total) {
        fx4 a = s4[ir[slot] * TV4 + t4];
        fx4 c = s4[jr[slot] * TV4 + t4];
        fx4 r = a - c;
        __builtin_nontemporal_store(r, &ob[(size_t)obase[slot] * TV4 + t4]);
        v += NT;
        slot += 10;
        t4 += 12;
        if (t4 >= TV4) { t4 -= TV4; ++slot; }
    }
}

extern "C" void kernel_launch(void* const* d_in, const int* in_sizes, int n_in,
                              void* d_out, int out_size, void* d_ws, size_t ws_size,
                              hipStream_t stream) {
    const float* x = (const float*)d_in[0];
    float* out = (float*)d_out;
    ts_sub_combo<<<dim3(NWG), dim3(NT), 0, stream>>>(
        (const fx4*)x, (fx4*)out);
}

// Round 13
// 101.185 us; speedup vs baseline: 1.3861x; 1.0554x over previous
//
#include <hip/hip_runtime.h>

// TsSub: out[b, p, t] = x[b, I[p], t*10] - x[b, J[p], t*10]
// x: (256, 64, 2000) f32, out: (256, 2016, 200) f32, (I,J)=triu_indices(64,k=1)
//
// R13: ONE block per batch b. Stage all 64 sampled rows into LDS (51.2 KB)
// exactly once -> read amplification exactly 1x (131 MB HBM fetch, nt loads,
// zero L2 dependence). Emit all 2016 pair rows, nt stores (R11: nt is +30us
// over cached). 256 blocks x 1024 threads, 16 waves/CU.

#define NF     64
#define T_OUT  200
#define NPAIR  2016
#define NB     256
#define RF4    500     // vec4 per x row
#define TV4    50      // vec4 per out row
#define NT     1024

typedef float fx4 __attribute__((ext_vector_type(4)));

__global__ __launch_bounds__(NT)
void ts_sub_b(const fx4* __restrict__ xv, fx4* __restrict__ out) {
    __shared__ __attribute__((aligned(16))) float sf[NF * T_OUT];  // 51.2 KB
    __shared__ unsigned char pi[NPAIR];
    __shared__ unsigned char pj[NPAIR];

    const int tid = threadIdx.x;
    const int b   = blockIdx.x;

    // --- pair table: closed-form triangular inversion (2 iters/thread) ---
    for (int p = tid; p < NPAIR; p += NT) {
        float d = 16129.0f - 8.0f * (float)p;          // 127^2 - 8p
        int i = (int)((127.0f - sqrtf(d)) * 0.5f);
        if (i < 0) i = 0;
        while (i > 0 && (i * (127 - i)) / 2 > p) --i;
        while (((i + 1) * (126 - i)) / 2 <= p) ++i;
        pi[p] = (unsigned char)i;
        pj[p] = (unsigned char)(p - (i * (127 - i)) / 2 + i + 1);
    }

    // --- stage all 64 sampled rows (each x-line read exactly once, nt) ---
    // k in [0,200): vec4 m = 5*(k>>1)+2*(k&1), sample = (k&1) ? .z : .x
    {
        const fx4* __restrict__ xb = xv + (size_t)b * (NF * RF4);
        int row = tid / T_OUT;
        int k   = tid - row * T_OUT;
        for (int idx = tid; idx < NF * T_OUT; idx += NT) {   // 12800
            fx4 v = __builtin_nontemporal_load(
                        &xb[row * RF4 + 5 * (k >> 1) + 2 * (k & 1)]);
            sf[row * T_OUT + k] = (k & 1) ? v.z : v.x;
            row += 5;                            // 1024 = 5*200 + 24
            k += 24;
            if (k >= T_OUT) { k -= T_OUT; ++row; }
        }
    }
    __syncthreads();

    // --- emit all 2016 pair rows x 50 vec4, nt stores ---
    const fx4* __restrict__ s4 = reinterpret_cast<const fx4*>(sf); // row stride 50
    fx4* __restrict__ ob = out + (size_t)b * (NPAIR * TV4);

    int p  = tid / TV4;
    int t4 = tid - p * TV4;
    for (int v = tid; v < NPAIR * TV4; v += NT) {        // 100800
        fx4 a = s4[pi[p] * TV4 + t4];
        fx4 c = s4[pj[p] * TV4 + t4];
        fx4 r = a - c;
        __builtin_nontemporal_store(r, &ob[(size_t)p * TV4 + t4]);
        p += 20;                                 // 1024 = 20*50 + 24
        t4 += 24;
        if (t4 >= TV4) { t4 -= TV4; ++p; }
    }
}

extern "C" void kernel_launch(void* const* d_in, const int* in_sizes, int n_in,
                              void* d_out, int out_size, void* d_ws, size_t ws_size,
                              hipStream_t stream) {
    const float* x = (const float*)d_in[0];
    float* out = (float*)d_out;
    ts_sub_b<<<dim3(NB), dim3(NT), 0, stream>>>((const fx4*)x, (fx4*)out);
}